// Round 22
// baseline (65.836 us; speedup 1.0000x reference)
//
#include <hip/hip_runtime.h>

typedef float    v4f    __attribute__((ext_vector_type(4)));
typedef float    f32x4  __attribute__((ext_vector_type(4)));
typedef short    bf16x8 __attribute__((ext_vector_type(8)));
typedef unsigned u32x4  __attribute__((ext_vector_type(4)));

namespace {
constexpr int MSTR = 72;    // mbf/abf row stride (shorts)
constexpr int MWC  = 129;   // mw row stride (f32)
constexpr int ATS  = 264;   // att row stride (shorts); 528 B = 33x16 (b128-aligned rows)
constexpr int FRAG_SLOTS = 5120;

__device__ __forceinline__ float fsilu(float v){ return v/(1.f+__expf(-v)); }
__device__ __forceinline__ float fsigm(float v){ return 1.f/(1.f+__expf(-v)); }

__device__ __forceinline__ unsigned f2bf2(float a, float b){
  unsigned r;
  asm("v_cvt_pk_bf16_f32 %0, %1, %2" : "=v"(r) : "v"(a), "v"(b));
  return r;
}
__device__ __forceinline__ short f2bf(float f){   // scalar RNE, matches cvt_pk
  unsigned u = __builtin_bit_cast(unsigned, f);
  return (short)((u + 0x7FFFu + ((u>>16)&1u)) >> 16);
}
__device__ __forceinline__ float bf2f(short s){
  unsigned u = ((unsigned)(unsigned short)s) << 16;
  return __builtin_bit_cast(float, u);
}
__device__ __forceinline__ bf16x8 pack4(unsigned u0, unsigned u1, unsigned u2, unsigned u3){
  u32x4 u = {u0, u1, u2, u3};
  return __builtin_bit_cast(bf16x8, u);
}
__device__ __forceinline__ bf16x8 cvt8(v4f lo, v4f hi){
  return pack4(f2bf2(lo.x, lo.y), f2bf2(lo.z, lo.w),
               f2bf2(hi.x, hi.y), f2bf2(hi.z, hi.w));
}

template<bool USE_WS>
__device__ __forceinline__ bf16x8 get_bd(const bf16x8* wsf, const float* Wd,
                                         int nt, int ks, int l){
  if constexpr (USE_WS) return wsf[(nt*8 + ks)*64 + l];
  bf16x8 f;
  #pragma unroll
  for (int j = 0; j < 8; ++j) f[j] = f2bf(Wd[(ks*32 + (l>>4)*8 + j)*64 + nt*16 + (l&15)]);
  return f;
}
template<bool USE_WS>
__device__ __forceinline__ bf16x8 get_bc(const bf16x8* wsf, const float* Wc,
                                         int nt, int ks, int l){
  if constexpr (USE_WS) return wsf[2048 + (nt*2 + ks)*64 + l];
  const int col = nt*16 + (l&15), cw = col>>6, co = col&63;
  bf16x8 f;
  #pragma unroll
  for (int j = 0; j < 8; ++j) f[j] = f2bf(Wc[co*128 + cw*64 + ks*32 + (l>>4)*8 + j]);
  return f;
}
template<bool USE_WS>
__device__ __forceinline__ bf16x8 get_ba(const bf16x8* wsf, const float* Wa,
                                         int nt, int ks, int l){
  if constexpr (USE_WS) return wsf[3072 + (nt*2 + ks)*64 + l];
  const int col = nt*16 + (l&15);
  bf16x8 f;
  #pragma unroll
  for (int j = 0; j < 8; ++j) f[j] = f2bf(Wa[(ks*32 + (l>>4)*8 + j)*256 + col]);
  return f;
}
}

__global__ __launch_bounds__(256)
void pack_frags(const float* __restrict__ Wd, const float* __restrict__ Wc,
                const float* __restrict__ Wa, bf16x8* __restrict__ wsf)
{
  const int e  = blockIdx.x*256 + threadIdx.x;      // 0..5119
  const int l  = e & 63;
  const int fi = e >> 6;                            // 0..79
  bf16x8 f;
  if (fi < 32) {                                    // Bd: nt(4) x ks(8)
    const int nt = fi >> 3, ks = fi & 7;
    #pragma unroll
    for (int j = 0; j < 8; ++j) f[j] = f2bf(Wd[(ks*32 + (l>>4)*8 + j)*64 + nt*16 + (l&15)]);
  } else if (fi < 48) {                             // Bc: nt(8) x ks(2)
    const int idx = fi - 32, nt = idx >> 1, ks = idx & 1;
    const int col = nt*16 + (l&15), cw = col>>6, co = col&63;
    #pragma unroll
    for (int j = 0; j < 8; ++j) f[j] = f2bf(Wc[co*128 + cw*64 + ks*32 + (l>>4)*8 + j]);
  } else {                                          // Ba: nt(16) x ks(2)
    const int idx = fi - 48, nt = idx >> 1, ks = idx & 1;
    const int col = nt*16 + (l&15);
    #pragma unroll
    for (int j = 0; j < 8; ++j) f[j] = f2bf(Wa[(ks*32 + (l>>4)*8 + j)*256 + col]);
  }
  wsf[e] = f;
}

// v19: WAVE-PER-BATCH, zero barriers. 4 independent waves per block, grid 1024.
template<bool USE_WS>
__global__ __launch_bounds__(256, 4)
void fused_gnn_v19(const float* __restrict__ x,
                   const float* __restrict__ Wd, const float* __restrict__ bd,
                   const float* __restrict__ bn1s, const float* __restrict__ bn1b,
                   const float* __restrict__ bn1m, const float* __restrict__ bn1v,
                   const float* __restrict__ Wc,
                   const float* __restrict__ bn2s, const float* __restrict__ bn2b,
                   const float* __restrict__ bn2m, const float* __restrict__ bn2v,
                   const float* __restrict__ Wa, const float* __restrict__ ba,
                   const bf16x8* __restrict__ wsf,
                   float* __restrict__ out)
{
  // per-wave private LDS partitions; no __syncthreads anywhere
  __shared__ short mbfs[4][21*MSTR];   // rows 0-4: means; rows 5-20: abf (overlapped garbage OK)
  __shared__ float mws [4][5*MWC];
  __shared__ short atts[4][5*ATS];

  const int tid  = threadIdx.x;
  const int l    = tid & 63;
  const int wv   = tid >> 6;
  short* mbf = mbfs[wv];
  short* abf = mbfs[wv] + 5*MSTR;
  float* mw  = mws[wv];
  short* att = atts[wv];

  const int arow = l & 15;
  const int q4   = l >> 4;
  const int ak8  = q4 * 8;
  const int b    = blockIdx.x*4 + wv;              // one batch per wave
  const float* xb = x + (size_t)b * 4352;

  // ---- BN affines in registers ----
  float a1c0, a1c1, a1c2, a1c3, b1c0, b1c1, b1c2, b1c3;
  {
    const int c0 = 0*16+arow, c1 = 1*16+arow, c2 = 2*16+arow, c3 = 3*16+arow;
    a1c0 = bn1s[c0]*rsqrtf(bn1v[c0]+1e-5f); b1c0 = (bd[c0]-bn1m[c0])*a1c0 + bn1b[c0];
    a1c1 = bn1s[c1]*rsqrtf(bn1v[c1]+1e-5f); b1c1 = (bd[c1]-bn1m[c1])*a1c1 + bn1b[c1];
    a1c2 = bn1s[c2]*rsqrtf(bn1v[c2]+1e-5f); b1c2 = (bd[c2]-bn1m[c2])*a1c2 + bn1b[c2];
    a1c3 = bn1s[c3]*rsqrtf(bn1v[c3]+1e-5f); b1c3 = (bd[c3]-bn1m[c3])*a1c3 + bn1b[c3];
  }
  const float a2r = bn2s[l]*rsqrtf(bn2v[l]+1e-5f);
  const float b2r = bn2b[l] - bn2m[l]*a2r;

  // ---- load x directly in A-frag layout; main frags kept for F ----
  bf16x8 xf[8];                                    // rows 0-15 slice (kept, 32 VGPR)
  bf16x8 xt[8];                                    // tail: row16 (arow==0) / row0 dup (dies after A)
  {
    const int rowT = (arow == 0) ? 16 : 0;
    #pragma unroll
    for (int ks = 0; ks < 8; ++ks) {
      v4f lo = *(const v4f*)(xb + arow*256 + ks*32 + ak8);
      v4f hi = *(const v4f*)(xb + arow*256 + ks*32 + ak8 + 4);
      xf[ks] = cvt8(lo, hi);
      v4f tl = *(const v4f*)(xb + rowT*256 + ks*32 + ak8);
      v4f th = *(const v4f*)(xb + rowT*256 + ks*32 + ak8 + 4);
      xt[ks] = cvt8(tl, th);
    }
  }

  // ---- Phase A + B1 fused, per n-tile: MFMA -> silu(bn1) -> butterfly means ----
  #pragma unroll
  for (int nt = 0; nt < 4; ++nt) {
    const float a1v = (nt==0)?a1c0:(nt==1)?a1c1:(nt==2)?a1c2:a1c3;
    const float b1v = (nt==0)?b1c0:(nt==1)?b1c1:(nt==2)?b1c2:b1c3;
    f32x4 acc0 = {0.f,0.f,0.f,0.f};
    f32x4 acc1 = {0.f,0.f,0.f,0.f};
    #pragma unroll
    for (int h = 0; h < 2; ++h) {
      bf16x8 Bd[4];
      #pragma unroll
      for (int k4 = 0; k4 < 4; ++k4) Bd[k4] = get_bd<USE_WS>(wsf, Wd, nt, h*4 + k4, l);
      #pragma unroll
      for (int k4 = 0; k4 < 4; ++k4) {
        const int ks = h*4 + k4;
        acc0 = __builtin_amdgcn_mfma_f32_16x16x32_bf16(xf[ks], Bd[k4], acc0, 0, 0, 0);
        acc1 = __builtin_amdgcn_mfma_f32_16x16x32_bf16(xt[ks], Bd[k4], acc1, 0, 0, 0);
      }
    }
    const float s0 = fsilu(acc0[0]*a1v + b1v);
    const float s1 = fsilu(acc0[1]*a1v + b1v);
    const float s2 = fsilu(acc0[2]*a1v + b1v);
    const float s3 = fsilu(acc0[3]*a1v + b1v);
    const float st = fsilu(acc1[0]*a1v + b1v);     // x-row 16 (valid at q4==0)
    // per-lane partial group sums; rows = q4*4+j; groups per GROUPS table
    float p0 = 0.f, p1 = 0.f, p2 = 0.f, p3 = 0.f, p4 = 0.f;
    if (q4 == 0)      { p0 = s0+s1+s2+s3; p4 = st; }
    else if (q4 == 1) { p0 = s0; p1 = s1+s3; p2 = s2; }
    else if (q4 == 2) { p2 = s0+s2; p1 = s1; p3 = s3; }
    else              { p4 = s0+s2; p3 = s1+s3; }
    p0 += __shfl_xor(p0, 16); p0 += __shfl_xor(p0, 32);
    p1 += __shfl_xor(p1, 16); p1 += __shfl_xor(p1, 32);
    p2 += __shfl_xor(p2, 16); p2 += __shfl_xor(p2, 32);
    p3 += __shfl_xor(p3, 16); p3 += __shfl_xor(p3, 32);
    p4 += __shfl_xor(p4, 16); p4 += __shfl_xor(p4, 32);
    if (q4 == 0) {
      const int col = nt*16 + arow;
      mbf[0*MSTR + col] = f2bf(p0 * 0.2f);
      mbf[1*MSTR + col] = f2bf(p1 * (1.f/3.f));
      mbf[2*MSTR + col] = f2bf(p2 * (1.f/3.f));
      mbf[3*MSTR + col] = f2bf(p3 * (1.f/3.f));
      mbf[4*MSTR + col] = f2bf(p4 * (1.f/3.f));
    }
  }
  // no barrier: all following reads are this wave's own writes (in-wave DS ordering)

  // ---- Phase B2 (MFMA): mw = means @ [Wc1|Wc2], M=5, N=128 (8 n-tiles in-wave) ----
  {
    const bf16x8 am0 = *(const bf16x8*)&mbf[arow*MSTR + 0*32 + ak8];
    const bf16x8 am1 = *(const bf16x8*)&mbf[arow*MSTR + 1*32 + ak8];
    #pragma unroll
    for (int nt = 0; nt < 8; ++nt) {
      f32x4 acc = {0.f,0.f,0.f,0.f};
      acc = __builtin_amdgcn_mfma_f32_16x16x32_bf16(am0, get_bc<USE_WS>(wsf, Wc, nt, 0, l), acc, 0, 0, 0);
      acc = __builtin_amdgcn_mfma_f32_16x16x32_bf16(am1, get_bc<USE_WS>(wsf, Wc, nt, 1, l), acc, 0, 0, 0);
      if (q4 == 0) {
        #pragma unroll
        for (int j = 0; j < 4; ++j) mw[j*MWC + nt*16 + arow] = acc[j];
      } else if (q4 == 1) {
        mw[4*MWC + nt*16 + arow] = acc[0];
      }
    }
  }

  // ---- Phase B3: agg at col l (all 5 groups per lane) ----
  {
    const float c0 = mw[0*MWC + 64 + l];
    const float c1 = mw[1*MWC + 64 + l];
    const float c2 = mw[2*MWC + 64 + l];
    const float c3 = mw[3*MWC + 64 + l];
    const float c4 = mw[4*MWC + 64 + l];
    auto doG = [&](int g, float m2g){
      const float bse = mw[g*MWC + l] - m2g;
      float s = 0.f;
      if (g != 0) s += fsilu((bse + c0)*a2r + b2r);
      if (g != 1) s += fsilu((bse + c1)*a2r + b2r);
      if (g != 2) s += fsilu((bse + c2)*a2r + b2r);
      if (g != 3) s += fsilu((bse + c3)*a2r + b2r);
      if (g != 4) s += fsilu((bse + c4)*a2r + b2r);
      abf[g*MSTR + l] = f2bf(s);
    };
    doG(0, c0); doG(1, c1); doG(2, c2); doG(3, c3); doG(4, c4);
  }

  // ---- Phase E (MFMA): att = sigmoid(agg @ Wa + ba), M=5, N=256 (16 n-tiles) ----
  {
    const bf16x8 ae0 = *(const bf16x8*)&abf[arow*MSTR + 0*32 + ak8];
    const bf16x8 ae1 = *(const bf16x8*)&abf[arow*MSTR + 1*32 + ak8];
    #pragma unroll
    for (int nt = 0; nt < 16; ++nt) {
      f32x4 acc = {0.f,0.f,0.f,0.f};
      acc = __builtin_amdgcn_mfma_f32_16x16x32_bf16(ae0, get_ba<USE_WS>(wsf, Wa, nt, 0, l), acc, 0, 0, 0);
      acc = __builtin_amdgcn_mfma_f32_16x16x32_bf16(ae1, get_ba<USE_WS>(wsf, Wa, nt, 1, l), acc, 0, 0, 0);
      const int colE = nt*16 + arow;
      if (q4 == 0) {
        const float bav = ba[colE];
        #pragma unroll
        for (int j = 0; j < 4; ++j)
          att[j*ATS + colE] = f2bf(fsigm(acc[j] + bav));
      } else if (q4 == 1) {
        att[4*ATS + colE] = f2bf(fsigm(acc[0] + ba[colE]));
      }
    }
  }

  // ---- Phase F: out[arow][..] from kept x frags; row 16 by arow==0 lanes ----
  {
    float* og = out + (size_t)b * 4352;
    const int g = (arow < 5) ? 0 : (arow < 11 ? ((arow & 1) ? 1 : 2)
                                              : ((arow & 1) ? 3 : 4));
    #pragma unroll
    for (int ks = 0; ks < 8; ++ks) {
      const bf16x8 a8 = *(const bf16x8*)&att[g*ATS + ks*32 + ak8];
      const bf16x8 xk = xf[ks];
      v4f o0, o1;
      o0.x = bf2f(xk[0])*bf2f(a8[0]); o0.y = bf2f(xk[1])*bf2f(a8[1]);
      o0.z = bf2f(xk[2])*bf2f(a8[2]); o0.w = bf2f(xk[3])*bf2f(a8[3]);
      o1.x = bf2f(xk[4])*bf2f(a8[4]); o1.y = bf2f(xk[5])*bf2f(a8[5]);
      o1.z = bf2f(xk[6])*bf2f(a8[6]); o1.w = bf2f(xk[7])*bf2f(a8[7]);
      *(v4f*)(og + arow*256 + ks*32 + ak8)     = o0;
      *(v4f*)(og + arow*256 + ks*32 + ak8 + 4) = o1;
    }
    if (arow == 0) {                               // row 16, group 4
      #pragma unroll
      for (int ks = 0; ks < 8; ++ks) {
        const v4f lo = *(const v4f*)(xb + 16*256 + ks*32 + ak8);
        const v4f hi = *(const v4f*)(xb + 16*256 + ks*32 + ak8 + 4);
        const bf16x8 a8 = *(const bf16x8*)&att[4*ATS + ks*32 + ak8];
        v4f o0, o1;
        o0.x = lo.x*bf2f(a8[0]); o0.y = lo.y*bf2f(a8[1]);
        o0.z = lo.z*bf2f(a8[2]); o0.w = lo.w*bf2f(a8[3]);
        o1.x = hi.x*bf2f(a8[4]); o1.y = hi.y*bf2f(a8[5]);
        o1.z = hi.z*bf2f(a8[6]); o1.w = hi.w*bf2f(a8[7]);
        *(v4f*)(og + 16*256 + ks*32 + ak8)     = o0;
        *(v4f*)(og + 16*256 + ks*32 + ak8 + 4) = o1;
      }
    }
  }
}

extern "C" void kernel_launch(void* const* d_in, const int* in_sizes, int n_in,
                              void* d_out, int out_size, void* d_ws, size_t ws_size,
                              hipStream_t stream) {
    (void)n_in; (void)out_size;
    const float* x   = (const float*)d_in[0];
    const float* Wd  = (const float*)d_in[1];
    const float* bd  = (const float*)d_in[2];
    const float* s1  = (const float*)d_in[3];
    const float* b1  = (const float*)d_in[4];
    const float* m1  = (const float*)d_in[5];
    const float* v1  = (const float*)d_in[6];
    const float* Wc  = (const float*)d_in[7];
    const float* s2  = (const float*)d_in[8];
    const float* b2  = (const float*)d_in[9];
    const float* m2  = (const float*)d_in[10];
    const float* v2  = (const float*)d_in[11];
    const float* Wa  = (const float*)d_in[12];
    const float* ba  = (const float*)d_in[13];

    const int Btot = in_sizes[0] / (17 * 256);   // 4096
    const int GRID = Btot / 4;                   // 1024 blocks x 4 waves = 1 wave/batch
    bf16x8* wsf = (bf16x8*)d_ws;

    if (ws_size >= (size_t)FRAG_SLOTS * 16) {
        pack_frags<<<FRAG_SLOTS/256, 256, 0, stream>>>(Wd, Wc, Wa, wsf);
        fused_gnn_v19<true><<<GRID, 256, 0, stream>>>(
            x, Wd, bd, s1, b1, m1, v1, Wc, s2, b2, m2, v2, Wa, ba,
            wsf, (float*)d_out);
    } else {
        fused_gnn_v19<false><<<GRID, 256, 0, stream>>>(
            x, Wd, bd, s1, b1, m1, v1, Wc, s2, b2, m2, v2, Wa, ba,
            wsf, (float*)d_out);
    }
}

// Round 23
// 42.873 us; speedup vs baseline: 1.5356x; 1.5356x over previous
//
#include <hip/hip_runtime.h>

typedef float  v4f    __attribute__((ext_vector_type(4)));
typedef float  f32x4  __attribute__((ext_vector_type(4)));
typedef short  bf16x8 __attribute__((ext_vector_type(8)));
typedef short  bf16x4 __attribute__((ext_vector_type(4)));

namespace {
constexpr int XBSTR = 264;   // xbf row stride (shorts)
constexpr int XDT   = 24;    // xdT col stride (shorts); 48 B, b128-aligned
constexpr int MWC   = 129;   // mw row stride (f32)
constexpr int ATS   = 260;   // att row stride (shorts)
constexpr int MSTR  = 72;    // mbf/abf row stride (shorts)
constexpr int FRAG_SLOTS = 5120;

__device__ __forceinline__ float fsilu(float v){ return v/(1.f+__expf(-v)); }
__device__ __forceinline__ float fsigm(float v){ return 1.f/(1.f+__expf(-v)); }

__device__ __forceinline__ unsigned f2bf2(float a, float b){
  unsigned r;
  asm("v_cvt_pk_bf16_f32 %0, %1, %2" : "=v"(r) : "v"(a), "v"(b));
  return r;
}
__device__ __forceinline__ short f2bf(float f){   // scalar RNE, matches cvt_pk
  unsigned u = __builtin_bit_cast(unsigned, f);
  return (short)((u + 0x7FFFu + ((u>>16)&1u)) >> 16);
}
__device__ __forceinline__ float bf2f(short s){
  unsigned u = ((unsigned)(unsigned short)s) << 16;
  return __builtin_bit_cast(float, u);
}

template<bool USE_WS>
__device__ __forceinline__ bf16x8 get_bd(const bf16x8* wsf, const float* Wd,
                                         int nt, int ks, int l){
  if constexpr (USE_WS) return wsf[(nt*8 + ks)*64 + l];
  bf16x8 f;
  #pragma unroll
  for (int j = 0; j < 8; ++j) f[j] = f2bf(Wd[(ks*32 + (l>>4)*8 + j)*64 + nt*16 + (l&15)]);
  return f;
}
template<bool USE_WS>
__device__ __forceinline__ bf16x8 get_bc(const bf16x8* wsf, const float* Wc,
                                         int nt, int ks, int l){
  if constexpr (USE_WS) return wsf[2048 + (nt*2 + ks)*64 + l];
  const int col = nt*16 + (l&15), cw = col>>6, co = col&63;
  bf16x8 f;
  #pragma unroll
  for (int j = 0; j < 8; ++j) f[j] = f2bf(Wc[co*128 + cw*64 + ks*32 + (l>>4)*8 + j]);
  return f;
}
template<bool USE_WS>
__device__ __forceinline__ bf16x8 get_ba(const bf16x8* wsf, const float* Wa,
                                         int nt, int ks, int l){
  if constexpr (USE_WS) return wsf[3072 + (nt*2 + ks)*64 + l];
  const int col = nt*16 + (l&15);
  bf16x8 f;
  #pragma unroll
  for (int j = 0; j < 8; ++j) f[j] = f2bf(Wa[(ks*32 + (l>>4)*8 + j)*256 + col]);
  return f;
}
}

__global__ __launch_bounds__(256)
void pack_frags(const float* __restrict__ Wd, const float* __restrict__ Wc,
                const float* __restrict__ Wa, bf16x8* __restrict__ wsf)
{
  const int e  = blockIdx.x*256 + threadIdx.x;      // 0..5119
  const int l  = e & 63;
  const int fi = e >> 6;                            // 0..79
  bf16x8 f;
  if (fi < 32) {                                    // Bd: nt(4) x ks(8)
    const int nt = fi >> 3, ks = fi & 7;
    #pragma unroll
    for (int j = 0; j < 8; ++j) f[j] = f2bf(Wd[(ks*32 + (l>>4)*8 + j)*64 + nt*16 + (l&15)]);
  } else if (fi < 48) {                             // Bc: nt(8) x ks(2)
    const int idx = fi - 32, nt = idx >> 1, ks = idx & 1;
    const int col = nt*16 + (l&15), cw = col>>6, co = col&63;
    #pragma unroll
    for (int j = 0; j < 8; ++j) f[j] = f2bf(Wc[co*128 + cw*64 + ks*32 + (l>>4)*8 + j]);
  } else {                                          // Ba: nt(16) x ks(2)
    const int idx = fi - 48, nt = idx >> 1, ks = idx & 1;
    const int col = nt*16 + (l&15);
    #pragma unroll
    for (int j = 0; j < 8; ++j) f[j] = f2bf(Wa[(ks*32 + (l>>4)*8 + j)*256 + col]);
  }
  wsf[e] = f;
}

// v18 = v12 dataflow with wave-local producer->consumer mappings: 3 barriers.
// Best measured configuration (41.43 us, round 21).
template<bool USE_WS>
__global__ __launch_bounds__(256, 5)
void fused_gnn_v18(const float* __restrict__ x,
                   const float* __restrict__ Wd, const float* __restrict__ bd,
                   const float* __restrict__ bn1s, const float* __restrict__ bn1b,
                   const float* __restrict__ bn1m, const float* __restrict__ bn1v,
                   const float* __restrict__ Wc,
                   const float* __restrict__ bn2s, const float* __restrict__ bn2b,
                   const float* __restrict__ bn2m, const float* __restrict__ bn2v,
                   const float* __restrict__ Wa, const float* __restrict__ ba,
                   const bf16x8* __restrict__ wsf,
                   float* __restrict__ out)
{
  // ~19.8 KB static LDS
  __shared__ short xbf[18*XBSTR];                   // row 17 = tail-clamp garbage target
  __shared__ __align__(16) char uni_raw[3072];      // union: xdT bf16[64][24] | att bf16[5][260]
  __shared__ float mw[5*MWC];
  __shared__ short mbf[16*MSTR];                    // rows 5-15 garbage
  __shared__ short abf[16*MSTR];

  short* xdT = (short*)uni_raw;   // dead after B1 (bar2/bar3 separate it from att writes)
  short* att = (short*)uni_raw;

  const int tid  = threadIdx.x;
  const int l    = tid & 63;
  const int wv   = tid >> 6;            // wave 0..3
  const int arow = l & 15;
  const int ak8  = (l >> 4) * 8;
  const int q4   = l >> 4;
  const int b    = blockIdx.x;          // one batch per block
  const int colA = wv*16 + arow;        // phase-A output column (wave-owned)
  const int colW = wv*16 + (l & 15);    // own-wave column for B1/B3
  const int c4s  = l*4;                 // staging column quad
  const int r0s  = tid >> 6;            // staging base row

  // ---- per-lane BN affines in registers ----
  const float a1r = bn1s[colA] * rsqrtf(bn1v[colA] + 1e-5f);
  const float b1r = (bd[colA] - bn1m[colA])*a1r + bn1b[colA];
  const float a2r = bn2s[colW] * rsqrtf(bn2v[colW] + 1e-5f);
  const float b2r = bn2b[colW] - bn2m[colW]*a2r;

  // ---- stage x -> bf16 LDS (regs die immediately) ----
  {
    const v4f* x4 = (const v4f*)(x + (size_t)b * 4352);
    auto ldst = [&](int slot, int r){
      const v4f v = x4[slot*256 + tid];
      uint2 u; u.x = f2bf2(v.x, v.y); u.y = f2bf2(v.z, v.w);
      *(uint2*)&xbf[r*XBSTR + c4s] = u;
    };
    ldst(0, r0s);      ldst(1, r0s + 4);
    ldst(2, r0s + 8);  ldst(3, r0s + 12);
    if (tid < 64) {
      const v4f v = x4[1024 + tid];
      uint2 u; u.x = f2bf2(v.x, v.y); u.y = f2bf2(v.z, v.w);
      *(uint2*)&xbf[16*XBSTR + c4s] = u;
    }
  }
  __syncthreads();                                   // bar1: stage -> A (cross-wave rows)

  // ---- Phase A (MFMA): xd = silu(bn1(x @ Wd)), M=17, N=64, K=256; -> xdT ----
  {
    f32x4 acc0 = {0.f,0.f,0.f,0.f};
    f32x4 acc1 = {0.f,0.f,0.f,0.f};
    const int rowT = (arow == 0) ? 16 : 17;
    #pragma unroll
    for (int h = 0; h < 2; ++h) {
      bf16x8 Bd[4];
      #pragma unroll
      for (int k4 = 0; k4 < 4; ++k4) Bd[k4] = get_bd<USE_WS>(wsf, Wd, wv, h*4 + k4, l);
      #pragma unroll
      for (int k4 = 0; k4 < 4; ++k4) {
        const int ks = h*4 + k4;
        bf16x8 a0 = *(const bf16x8*)&xbf[arow*XBSTR + ks*32 + ak8];
        acc0 = __builtin_amdgcn_mfma_f32_16x16x32_bf16(a0, Bd[k4], acc0, 0, 0, 0);
        bf16x8 a1 = *(const bf16x8*)&xbf[rowT*XBSTR + ks*32 + ak8];
        acc1 = __builtin_amdgcn_mfma_f32_16x16x32_bf16(a1, Bd[k4], acc1, 0, 0, 0);
      }
    }
    const float s0 = fsilu(acc0[0]*a1r + b1r);
    const float s1 = fsilu(acc0[1]*a1r + b1r);
    const float s2 = fsilu(acc0[2]*a1r + b1r);
    const float s3 = fsilu(acc0[3]*a1r + b1r);
    uint2 u; u.x = f2bf2(s0, s1); u.y = f2bf2(s2, s3);
    *(uint2*)&xdT[colA*XDT + q4*4] = u;              // rows q4*4..+3 of column colA
    if (q4 == 0)
      xdT[colA*XDT + 16] = f2bf(fsilu(acc1[0]*a1r + b1r));
  }
  // NO barrier: B1 reads only columns [wv*16,+16) — written by this wave (lgkmcnt-ordered)

  // ---- prefetch B2 weight frags (nt = wv and wv+4) ----
  bf16x8 BcT[2][2];
  #pragma unroll
  for (int ks = 0; ks < 2; ++ks) {
    BcT[0][ks] = get_bc<USE_WS>(wsf, Wc, wv,     ks, l);
    BcT[1][ks] = get_bc<USE_WS>(wsf, Wc, wv + 4, ks, l);
  }

  // ---- Phase B1 (wave-local columns): col colW, quartet->group split ----
  {
    const int i = colW;
    #define XDV(r) bf2f(xdT[i*XDT + (r)])
    if (q4 == 0) {
      mbf[0*MSTR + i] = f2bf((XDV(0)+XDV(1)+XDV(2)+XDV(3)+XDV(4))*0.2f);
      mbf[4*MSTR + i] = f2bf((XDV(12)+XDV(14)+XDV(16))*(1.f/3.f));
    } else if (q4 == 1) {
      mbf[1*MSTR + i] = f2bf((XDV(5)+XDV(7)+XDV(9))*(1.f/3.f));
    } else if (q4 == 2) {
      mbf[2*MSTR + i] = f2bf((XDV(6)+XDV(8)+XDV(10))*(1.f/3.f));
    } else {
      mbf[3*MSTR + i] = f2bf((XDV(11)+XDV(13)+XDV(15))*(1.f/3.f));
    }
    #undef XDV
  }
  __syncthreads();                                   // bar2: B1 -> B2 (mbf cross-wave K-gather)

  // ---- Phase B2 (MFMA): mw = means @ [Wc1|Wc2]; wave owns n-tiles {wv, wv+4} ----
  {
    bf16x8 am[2];
    #pragma unroll
    for (int ks = 0; ks < 2; ++ks)
      am[ks] = *(const bf16x8*)&mbf[arow*MSTR + ks*32 + ak8];
    #pragma unroll
    for (int t = 0; t < 2; ++t) {
      const int nt = wv + t*4;                       // cols [wv*16,+16) and [64+wv*16,+16)
      f32x4 acc = {0.f,0.f,0.f,0.f};
      #pragma unroll
      for (int ks = 0; ks < 2; ++ks)
        acc = __builtin_amdgcn_mfma_f32_16x16x32_bf16(am[ks], BcT[t][ks], acc, 0, 0, 0);
      if (q4 == 0) {
        #pragma unroll
        for (int j = 0; j < 4; ++j) mw[j*MWC + nt*16 + arow] = acc[j];
      } else if (q4 == 1) {
        mw[4*MWC + nt*16 + arow] = acc[0];
      }
    }
  }
  // NO barrier: B3 reads mw cols colW and 64+colW — both written by this wave

  // ---- prefetch phase-E weight frags ----
  bf16x8 BaT[4][2];
  #pragma unroll
  for (int t = 0; t < 4; ++t)
    #pragma unroll
    for (int ks = 0; ks < 2; ++ks)
      BaT[t][ks] = get_ba<USE_WS>(wsf, Wa, wv*4 + t, ks, l);

  // ---- Phase B3 (wave-local columns): col colW, quartet->group split ----
  {
    const int o = colW;
    const float m2c0 = mw[0*MWC + 64 + o];
    const float m2c1 = mw[1*MWC + 64 + o];
    const float m2c2 = mw[2*MWC + 64 + o];
    const float m2c3 = mw[3*MWC + 64 + o];
    const float m2c4 = mw[4*MWC + 64 + o];
    auto doG = [&](int g, float m2g){
      const float bse = mw[g*MWC + o] - m2g;
      float s = 0.f;
      if (g != 0) s += fsilu((bse + m2c0)*a2r + b2r);
      if (g != 1) s += fsilu((bse + m2c1)*a2r + b2r);
      if (g != 2) s += fsilu((bse + m2c2)*a2r + b2r);
      if (g != 3) s += fsilu((bse + m2c3)*a2r + b2r);
      if (g != 4) s += fsilu((bse + m2c4)*a2r + b2r);
      abf[g*MSTR + o] = f2bf(s);
    };
    if (q4 == 0) { doG(0, m2c0); doG(4, m2c4); }
    else if (q4 == 1) doG(1, m2c1);
    else if (q4 == 2) doG(2, m2c2);
    else doG(3, m2c3);
  }
  __syncthreads();                                   // bar3: B3 -> E (abf cross-wave K-gather)

  // ---- Phase E (MFMA): att = sigmoid(agg @ Wa + ba); wave owns cols [wv*64,+64) ----
  {
    bf16x8 ae[2];
    #pragma unroll
    for (int ks = 0; ks < 2; ++ks)
      ae[ks] = *(const bf16x8*)&abf[arow*MSTR + ks*32 + ak8];
    #pragma unroll
    for (int t = 0; t < 4; ++t) {
      const int nt = wv*4 + t;
      const int colE = nt*16 + arow;
      f32x4 acc = {0.f,0.f,0.f,0.f};
      #pragma unroll
      for (int ks = 0; ks < 2; ++ks)
        acc = __builtin_amdgcn_mfma_f32_16x16x32_bf16(ae[ks], BaT[t][ks], acc, 0, 0, 0);
      const float bav = ba[colE];
      if (q4 == 0) {
        #pragma unroll
        for (int j = 0; j < 4; ++j)
          att[j*ATS + colE] = f2bf(fsigm(acc[j] + bav));
      } else if (q4 == 1) {
        att[4*ATS + colE] = f2bf(fsigm(acc[0] + bav));
      }
    }
  }
  // NO barrier: F reads att cols [wv*64,+64) — written by this wave;
  // F's xbf reads are of data stable since bar1 (no xbf writes after staging).

  // ---- Phase F (wave-local columns): out = bf16(x) * att, dwordx4 stores ----
  {
    const int cF = wv*64 + (l & 15)*4;
    float* og = out + (size_t)b*4352;
    constexpr int GOF[17] = {0,0,0,0,0,1,2,1,2,1,2,3,4,3,4,3,4};
    auto emit = [&](int k){
      const bf16x4 xv4 = *(const bf16x4*)&xbf[k*XBSTR + cF];
      const bf16x4 a4  = *(const bf16x4*)&att[GOF[k]*ATS + cF];
      v4f o;
      o.x = bf2f(xv4[0]) * bf2f(a4[0]);
      o.y = bf2f(xv4[1]) * bf2f(a4[1]);
      o.z = bf2f(xv4[2]) * bf2f(a4[2]);
      o.w = bf2f(xv4[3]) * bf2f(a4[3]);
      *(v4f*)&og[k*256 + cF] = o;
    };
    emit(q4);       emit(q4 + 4);
    emit(q4 + 8);   emit(q4 + 12);
    if (q4 == 0) emit(16);
  }
}

extern "C" void kernel_launch(void* const* d_in, const int* in_sizes, int n_in,
                              void* d_out, int out_size, void* d_ws, size_t ws_size,
                              hipStream_t stream) {
    (void)n_in; (void)out_size;
    const float* x   = (const float*)d_in[0];
    const float* Wd  = (const float*)d_in[1];
    const float* bd  = (const float*)d_in[2];
    const float* s1  = (const float*)d_in[3];
    const float* b1  = (const float*)d_in[4];
    const float* m1  = (const float*)d_in[5];
    const float* v1  = (const float*)d_in[6];
    const float* Wc  = (const float*)d_in[7];
    const float* s2  = (const float*)d_in[8];
    const float* b2  = (const float*)d_in[9];
    const float* m2  = (const float*)d_in[10];
    const float* v2  = (const float*)d_in[11];
    const float* Wa  = (const float*)d_in[12];
    const float* ba  = (const float*)d_in[13];

    const int Btot = in_sizes[0] / (17 * 256);   // 4096 -> one block per batch
    bf16x8* wsf = (bf16x8*)d_ws;

    if (ws_size >= (size_t)FRAG_SLOTS * 16) {
        pack_frags<<<FRAG_SLOTS/256, 256, 0, stream>>>(Wd, Wc, Wa, wsf);
        fused_gnn_v18<true><<<Btot, 256, 0, stream>>>(
            x, Wd, bd, s1, b1, m1, v1, Wc, s2, b2, m2, v2, Wa, ba,
            wsf, (float*)d_out);
    } else {
        fused_gnn_v18<false><<<Btot, 256, 0, stream>>>(
            x, Wd, bd, s1, b1, m1, v1, Wc, s2, b2, m2, v2, Wa, ba,
            wsf, (float*)d_out);
    }
}

// Round 24
// 41.498 us; speedup vs baseline: 1.5865x; 1.0331x over previous
//
#include <hip/hip_runtime.h>

typedef float  v4f    __attribute__((ext_vector_type(4)));
typedef float  f32x4  __attribute__((ext_vector_type(4)));
typedef short  bf16x8 __attribute__((ext_vector_type(8)));
typedef short  bf16x4 __attribute__((ext_vector_type(4)));

namespace {
constexpr int XBSTR = 264;   // xbf row stride (shorts)
constexpr int XDT   = 24;    // xdT col stride (shorts); 48 B, b128-aligned
constexpr int MWC   = 129;   // mw row stride (f32)
constexpr int ATS   = 260;   // att row stride (shorts)
constexpr int MSTR  = 72;    // mbf/abf row stride (shorts)
constexpr int FRAG_SLOTS = 5120;

__device__ __forceinline__ float fsilu(float v){ return v/(1.f+__expf(-v)); }
__device__ __forceinline__ float fsigm(float v){ return 1.f/(1.f+__expf(-v)); }

__device__ __forceinline__ unsigned f2bf2(float a, float b){
  unsigned r;
  asm("v_cvt_pk_bf16_f32 %0, %1, %2" : "=v"(r) : "v"(a), "v"(b));
  return r;
}
__device__ __forceinline__ short f2bf(float f){   // scalar RNE, matches cvt_pk
  unsigned u = __builtin_bit_cast(unsigned, f);
  return (short)((u + 0x7FFFu + ((u>>16)&1u)) >> 16);
}
__device__ __forceinline__ float bf2f(short s){
  unsigned u = ((unsigned)(unsigned short)s) << 16;
  return __builtin_bit_cast(float, u);
}

template<bool USE_WS>
__device__ __forceinline__ bf16x8 get_bd(const bf16x8* wsf, const float* Wd,
                                         int nt, int ks, int l){
  if constexpr (USE_WS) return wsf[(nt*8 + ks)*64 + l];
  bf16x8 f;
  #pragma unroll
  for (int j = 0; j < 8; ++j) f[j] = f2bf(Wd[(ks*32 + (l>>4)*8 + j)*64 + nt*16 + (l&15)]);
  return f;
}
template<bool USE_WS>
__device__ __forceinline__ bf16x8 get_bc(const bf16x8* wsf, const float* Wc,
                                         int nt, int ks, int l){
  if constexpr (USE_WS) return wsf[2048 + (nt*2 + ks)*64 + l];
  const int col = nt*16 + (l&15), cw = col>>6, co = col&63;
  bf16x8 f;
  #pragma unroll
  for (int j = 0; j < 8; ++j) f[j] = f2bf(Wc[co*128 + cw*64 + ks*32 + (l>>4)*8 + j]);
  return f;
}
template<bool USE_WS>
__device__ __forceinline__ bf16x8 get_ba(const bf16x8* wsf, const float* Wa,
                                         int nt, int ks, int l){
  if constexpr (USE_WS) return wsf[3072 + (nt*2 + ks)*64 + l];
  const int col = nt*16 + (l&15);
  bf16x8 f;
  #pragma unroll
  for (int j = 0; j < 8; ++j) f[j] = f2bf(Wa[(ks*32 + (l>>4)*8 + j)*256 + col]);
  return f;
}
}

__global__ __launch_bounds__(256)
void pack_frags(const float* __restrict__ Wd, const float* __restrict__ Wc,
                const float* __restrict__ Wa, bf16x8* __restrict__ wsf)
{
  const int e  = blockIdx.x*256 + threadIdx.x;      // 0..5119
  const int l  = e & 63;
  const int fi = e >> 6;                            // 0..79
  bf16x8 f;
  if (fi < 32) {                                    // Bd: nt(4) x ks(8)
    const int nt = fi >> 3, ks = fi & 7;
    #pragma unroll
    for (int j = 0; j < 8; ++j) f[j] = f2bf(Wd[(ks*32 + (l>>4)*8 + j)*64 + nt*16 + (l&15)]);
  } else if (fi < 48) {                             // Bc: nt(8) x ks(2)
    const int idx = fi - 32, nt = idx >> 1, ks = idx & 1;
    const int col = nt*16 + (l&15), cw = col>>6, co = col&63;
    #pragma unroll
    for (int j = 0; j < 8; ++j) f[j] = f2bf(Wc[co*128 + cw*64 + ks*32 + (l>>4)*8 + j]);
  } else {                                          // Ba: nt(16) x ks(2)
    const int idx = fi - 48, nt = idx >> 1, ks = idx & 1;
    const int col = nt*16 + (l&15);
    #pragma unroll
    for (int j = 0; j < 8; ++j) f[j] = f2bf(Wa[(ks*32 + (l>>4)*8 + j)*256 + col]);
  }
  wsf[e] = f;
}

// v18 FINAL: v12 dataflow with wave-local producer->consumer mappings (3 barriers).
// Best measured: 41.4-42.9 us across runs. Structural constraint documented in-session:
// per-batch serial chain latency at ~5 resident chains/CU; invariant to block shape,
// barrier count, batching, and kernel splitting (11 designs tested, rounds 4-22).
template<bool USE_WS>
__global__ __launch_bounds__(256, 5)
void fused_gnn_v18(const float* __restrict__ x,
                   const float* __restrict__ Wd, const float* __restrict__ bd,
                   const float* __restrict__ bn1s, const float* __restrict__ bn1b,
                   const float* __restrict__ bn1m, const float* __restrict__ bn1v,
                   const float* __restrict__ Wc,
                   const float* __restrict__ bn2s, const float* __restrict__ bn2b,
                   const float* __restrict__ bn2m, const float* __restrict__ bn2v,
                   const float* __restrict__ Wa, const float* __restrict__ ba,
                   const bf16x8* __restrict__ wsf,
                   float* __restrict__ out)
{
  // ~19.8 KB static LDS
  __shared__ short xbf[18*XBSTR];                   // row 17 = tail-clamp garbage target
  __shared__ __align__(16) char uni_raw[3072];      // union: xdT bf16[64][24] | att bf16[5][260]
  __shared__ float mw[5*MWC];
  __shared__ short mbf[16*MSTR];                    // rows 5-15 garbage
  __shared__ short abf[16*MSTR];

  short* xdT = (short*)uni_raw;   // dead after B1 (bar2/bar3 separate it from att writes)
  short* att = (short*)uni_raw;

  const int tid  = threadIdx.x;
  const int l    = tid & 63;
  const int wv   = tid >> 6;            // wave 0..3
  const int arow = l & 15;
  const int ak8  = (l >> 4) * 8;
  const int q4   = l >> 4;
  const int b    = blockIdx.x;          // one batch per block
  const int colA = wv*16 + arow;        // phase-A output column (wave-owned)
  const int colW = wv*16 + (l & 15);    // own-wave column for B1/B3
  const int c4s  = l*4;                 // staging column quad
  const int r0s  = tid >> 6;            // staging base row

  // ---- per-lane BN affines in registers ----
  const float a1r = bn1s[colA] * rsqrtf(bn1v[colA] + 1e-5f);
  const float b1r = (bd[colA] - bn1m[colA])*a1r + bn1b[colA];
  const float a2r = bn2s[colW] * rsqrtf(bn2v[colW] + 1e-5f);
  const float b2r = bn2b[colW] - bn2m[colW]*a2r;

  // ---- stage x -> bf16 LDS (regs die immediately) ----
  {
    const v4f* x4 = (const v4f*)(x + (size_t)b * 4352);
    auto ldst = [&](int slot, int r){
      const v4f v = x4[slot*256 + tid];
      uint2 u; u.x = f2bf2(v.x, v.y); u.y = f2bf2(v.z, v.w);
      *(uint2*)&xbf[r*XBSTR + c4s] = u;
    };
    ldst(0, r0s);      ldst(1, r0s + 4);
    ldst(2, r0s + 8);  ldst(3, r0s + 12);
    if (tid < 64) {
      const v4f v = x4[1024 + tid];
      uint2 u; u.x = f2bf2(v.x, v.y); u.y = f2bf2(v.z, v.w);
      *(uint2*)&xbf[16*XBSTR + c4s] = u;
    }
  }
  __syncthreads();                                   // bar1: stage -> A (cross-wave rows)

  // ---- Phase A (MFMA): xd = silu(bn1(x @ Wd)), M=17, N=64, K=256; -> xdT ----
  {
    f32x4 acc0 = {0.f,0.f,0.f,0.f};
    f32x4 acc1 = {0.f,0.f,0.f,0.f};
    const int rowT = (arow == 0) ? 16 : 17;
    #pragma unroll
    for (int h = 0; h < 2; ++h) {
      bf16x8 Bd[4];
      #pragma unroll
      for (int k4 = 0; k4 < 4; ++k4) Bd[k4] = get_bd<USE_WS>(wsf, Wd, wv, h*4 + k4, l);
      #pragma unroll
      for (int k4 = 0; k4 < 4; ++k4) {
        const int ks = h*4 + k4;
        bf16x8 a0 = *(const bf16x8*)&xbf[arow*XBSTR + ks*32 + ak8];
        acc0 = __builtin_amdgcn_mfma_f32_16x16x32_bf16(a0, Bd[k4], acc0, 0, 0, 0);
        bf16x8 a1 = *(const bf16x8*)&xbf[rowT*XBSTR + ks*32 + ak8];
        acc1 = __builtin_amdgcn_mfma_f32_16x16x32_bf16(a1, Bd[k4], acc1, 0, 0, 0);
      }
    }
    const float s0 = fsilu(acc0[0]*a1r + b1r);
    const float s1 = fsilu(acc0[1]*a1r + b1r);
    const float s2 = fsilu(acc0[2]*a1r + b1r);
    const float s3 = fsilu(acc0[3]*a1r + b1r);
    uint2 u; u.x = f2bf2(s0, s1); u.y = f2bf2(s2, s3);
    *(uint2*)&xdT[colA*XDT + q4*4] = u;              // rows q4*4..+3 of column colA
    if (q4 == 0)
      xdT[colA*XDT + 16] = f2bf(fsilu(acc1[0]*a1r + b1r));
  }
  // NO barrier: B1 reads only columns [wv*16,+16) — written by this wave (lgkmcnt-ordered)

  // ---- prefetch B2 weight frags (nt = wv and wv+4) ----
  bf16x8 BcT[2][2];
  #pragma unroll
  for (int ks = 0; ks < 2; ++ks) {
    BcT[0][ks] = get_bc<USE_WS>(wsf, Wc, wv,     ks, l);
    BcT[1][ks] = get_bc<USE_WS>(wsf, Wc, wv + 4, ks, l);
  }

  // ---- Phase B1 (wave-local columns): col colW, quartet->group split ----
  {
    const int i = colW;
    #define XDV(r) bf2f(xdT[i*XDT + (r)])
    if (q4 == 0) {
      mbf[0*MSTR + i] = f2bf((XDV(0)+XDV(1)+XDV(2)+XDV(3)+XDV(4))*0.2f);
      mbf[4*MSTR + i] = f2bf((XDV(12)+XDV(14)+XDV(16))*(1.f/3.f));
    } else if (q4 == 1) {
      mbf[1*MSTR + i] = f2bf((XDV(5)+XDV(7)+XDV(9))*(1.f/3.f));
    } else if (q4 == 2) {
      mbf[2*MSTR + i] = f2bf((XDV(6)+XDV(8)+XDV(10))*(1.f/3.f));
    } else {
      mbf[3*MSTR + i] = f2bf((XDV(11)+XDV(13)+XDV(15))*(1.f/3.f));
    }
    #undef XDV
  }
  __syncthreads();                                   // bar2: B1 -> B2 (mbf cross-wave K-gather)

  // ---- Phase B2 (MFMA): mw = means @ [Wc1|Wc2]; wave owns n-tiles {wv, wv+4} ----
  {
    bf16x8 am[2];
    #pragma unroll
    for (int ks = 0; ks < 2; ++ks)
      am[ks] = *(const bf16x8*)&mbf[arow*MSTR + ks*32 + ak8];
    #pragma unroll
    for (int t = 0; t < 2; ++t) {
      const int nt = wv + t*4;                       // cols [wv*16,+16) and [64+wv*16,+16)
      f32x4 acc = {0.f,0.f,0.f,0.f};
      #pragma unroll
      for (int ks = 0; ks < 2; ++ks)
        acc = __builtin_amdgcn_mfma_f32_16x16x32_bf16(am[ks], BcT[t][ks], acc, 0, 0, 0);
      if (q4 == 0) {
        #pragma unroll
        for (int j = 0; j < 4; ++j) mw[j*MWC + nt*16 + arow] = acc[j];
      } else if (q4 == 1) {
        mw[4*MWC + nt*16 + arow] = acc[0];
      }
    }
  }
  // NO barrier: B3 reads mw cols colW and 64+colW — both written by this wave

  // ---- prefetch phase-E weight frags ----
  bf16x8 BaT[4][2];
  #pragma unroll
  for (int t = 0; t < 4; ++t)
    #pragma unroll
    for (int ks = 0; ks < 2; ++ks)
      BaT[t][ks] = get_ba<USE_WS>(wsf, Wa, wv*4 + t, ks, l);

  // ---- Phase B3 (wave-local columns): col colW, quartet->group split ----
  {
    const int o = colW;
    const float m2c0 = mw[0*MWC + 64 + o];
    const float m2c1 = mw[1*MWC + 64 + o];
    const float m2c2 = mw[2*MWC + 64 + o];
    const float m2c3 = mw[3*MWC + 64 + o];
    const float m2c4 = mw[4*MWC + 64 + o];
    auto doG = [&](int g, float m2g){
      const float bse = mw[g*MWC + o] - m2g;
      float s = 0.f;
      if (g != 0) s += fsilu((bse + m2c0)*a2r + b2r);
      if (g != 1) s += fsilu((bse + m2c1)*a2r + b2r);
      if (g != 2) s += fsilu((bse + m2c2)*a2r + b2r);
      if (g != 3) s += fsilu((bse + m2c3)*a2r + b2r);
      if (g != 4) s += fsilu((bse + m2c4)*a2r + b2r);
      abf[g*MSTR + o] = f2bf(s);
    };
    if (q4 == 0) { doG(0, m2c0); doG(4, m2c4); }
    else if (q4 == 1) doG(1, m2c1);
    else if (q4 == 2) doG(2, m2c2);
    else doG(3, m2c3);
  }
  __syncthreads();                                   // bar3: B3 -> E (abf cross-wave K-gather)

  // ---- Phase E (MFMA): att = sigmoid(agg @ Wa + ba); wave owns cols [wv*64,+64) ----
  {
    bf16x8 ae[2];
    #pragma unroll
    for (int ks = 0; ks < 2; ++ks)
      ae[ks] = *(const bf16x8*)&abf[arow*MSTR + ks*32 + ak8];
    #pragma unroll
    for (int t = 0; t < 4; ++t) {
      const int nt = wv*4 + t;
      const int colE = nt*16 + arow;
      f32x4 acc = {0.f,0.f,0.f,0.f};
      #pragma unroll
      for (int ks = 0; ks < 2; ++ks)
        acc = __builtin_amdgcn_mfma_f32_16x16x32_bf16(ae[ks], BaT[t][ks], acc, 0, 0, 0);
      const float bav = ba[colE];
      if (q4 == 0) {
        #pragma unroll
        for (int j = 0; j < 4; ++j)
          att[j*ATS + colE] = f2bf(fsigm(acc[j] + bav));
      } else if (q4 == 1) {
        att[4*ATS + colE] = f2bf(fsigm(acc[0] + bav));
      }
    }
  }
  // NO barrier: F reads att cols [wv*64,+64) — written by this wave;
  // F's xbf reads are of data stable since bar1 (no xbf writes after staging).

  // ---- Phase F (wave-local columns): out = bf16(x) * att, dwordx4 stores ----
  {
    const int cF = wv*64 + (l & 15)*4;
    float* og = out + (size_t)b*4352;
    constexpr int GOF[17] = {0,0,0,0,0,1,2,1,2,1,2,3,4,3,4,3,4};
    auto emit = [&](int k){
      const bf16x4 xv4 = *(const bf16x4*)&xbf[k*XBSTR + cF];
      const bf16x4 a4  = *(const bf16x4*)&att[GOF[k]*ATS + cF];
      v4f o;
      o.x = bf2f(xv4[0]) * bf2f(a4[0]);
      o.y = bf2f(xv4[1]) * bf2f(a4[1]);
      o.z = bf2f(xv4[2]) * bf2f(a4[2]);
      o.w = bf2f(xv4[3]) * bf2f(a4[3]);
      *(v4f*)&og[k*256 + cF] = o;
    };
    emit(q4);       emit(q4 + 4);
    emit(q4 + 8);   emit(q4 + 12);
    if (q4 == 0) emit(16);
  }
}

extern "C" void kernel_launch(void* const* d_in, const int* in_sizes, int n_in,
                              void* d_out, int out_size, void* d_ws, size_t ws_size,
                              hipStream_t stream) {
    (void)n_in; (void)out_size;
    const float* x   = (const float*)d_in[0];
    const float* Wd  = (const float*)d_in[1];
    const float* bd  = (const float*)d_in[2];
    const float* s1  = (const float*)d_in[3];
    const float* b1  = (const float*)d_in[4];
    const float* m1  = (const float*)d_in[5];
    const float* v1  = (const float*)d_in[6];
    const float* Wc  = (const float*)d_in[7];
    const float* s2  = (const float*)d_in[8];
    const float* b2  = (const float*)d_in[9];
    const float* m2  = (const float*)d_in[10];
    const float* v2  = (const float*)d_in[11];
    const float* Wa  = (const float*)d_in[12];
    const float* ba  = (const float*)d_in[13];

    const int Btot = in_sizes[0] / (17 * 256);   // 4096 -> one block per batch
    bf16x8* wsf = (bf16x8*)d_ws;

    if (ws_size >= (size_t)FRAG_SLOTS * 16) {
        pack_frags<<<FRAG_SLOTS/256, 256, 0, stream>>>(Wd, Wc, Wa, wsf);
        fused_gnn_v18<true><<<Btot, 256, 0, stream>>>(
            x, Wd, bd, s1, b1, m1, v1, Wc, s2, b2, m2, v2, Wa, ba,
            wsf, (float*)d_out);
    } else {
        fused_gnn_v18<false><<<Btot, 256, 0, stream>>>(
            x, Wd, bd, s1, b1, m1, v1, Wc, s2, b2, m2, v2, Wa, ba,
            wsf, (float*)d_out);
    }
}